// Round 12
// baseline (498.451 us; speedup 1.0000x reference)
//
#include <hip/hip_runtime.h>
#include <stdint.h>

#define N_NODES 50000
#define DD 256
#define SS 25

typedef unsigned short u16;
typedef __attribute__((ext_vector_type(8))) __bf16 bf16x8;
typedef __attribute__((ext_vector_type(4))) float f32x4;

__device__ __forceinline__ u16 f2bf(float f) {  // round-to-nearest-even
    union { float f; uint32_t i; } c;
    c.f = f;
    uint32_t r = c.i + 0x7fffu + ((c.i >> 16) & 1u);
    return (u16)(r >> 16);
}

// packed max of 2 non-negative bf16 (bit patterns monotone, sign bit 0 -> signed i16 max is exact)
__device__ __forceinline__ uint4 pkmax4(uint4 a, uint4 b) {
    uint4 d;
    asm("v_pk_max_i16 %0, %1, %2" : "=v"(d.x) : "v"(a.x), "v"(b.x));
    asm("v_pk_max_i16 %0, %1, %2" : "=v"(d.y) : "v"(a.y), "v"(b.y));
    asm("v_pk_max_i16 %0, %1, %2" : "=v"(d.z) : "v"(a.z), "v"(b.z));
    asm("v_pk_max_i16 %0, %1, %2" : "=v"(d.w) : "v"(a.w), "v"(b.w));
    return d;
}

__device__ __forceinline__ void gld16(void* lds, const void* g) {
    __builtin_amdgcn_global_load_lds(
        (const __attribute__((address_space(1))) uint32_t*)g,
        (__attribute__((address_space(3))) uint32_t*)lds, 16, 0, 0);
}

// ---- f32 -> bf16 elementwise (exact: grid*block*4 == n) ----
__global__ __launch_bounds__(256) void cvt_f32_bf16_k(const float4* __restrict__ in,
                                                      u16* __restrict__ out) {
    int i = blockIdx.x * 256 + threadIdx.x;
    float4 v = in[i];
    uint2 o;
    o.x = (uint32_t)f2bf(v.x) | ((uint32_t)f2bf(v.y) << 16);
    o.y = (uint32_t)f2bf(v.z) | ((uint32_t)f2bf(v.w) << 16);
    *reinterpret_cast<uint2*>(out + (size_t)i * 4) = o;
}

// ---- weight f32 [K][256] -> bf16 MFMA B-fragment layout ----
__global__ __launch_bounds__(256) void cvt_w_k(const float* __restrict__ W,
                                               u16* __restrict__ out, int KT) {
    int t = blockIdx.x * 256 + threadIdx.x;
    if (t >= KT * 16 * 64) return;
    int lane = t & 63;
    int ct = (t >> 6) & 15;
    int kt = t >> 10;
    int k0 = kt * 32 + (lane >> 4) * 8;
    int col = ct * 16 + (lane & 15);
    u16 r[8];
#pragma unroll
    for (int e = 0; e < 8; e++) r[e] = f2bf(W[(size_t)(k0 + e) * DD + col]);
    uint4 v;
    v.x = (uint32_t)r[0] | ((uint32_t)r[1] << 16);
    v.y = (uint32_t)r[2] | ((uint32_t)r[3] << 16);
    v.z = (uint32_t)r[4] | ((uint32_t)r[5] << 16);
    v.w = (uint32_t)r[6] | ((uint32_t)r[7] << 16);
    *reinterpret_cast<uint4*>(out + (size_t)t * 8) = v;
}

// ---- XCD-sliced gather + max-pool (R7-proven, unchanged) ----
__global__ __launch_bounds__(256) void gather_xcd_k(const u16* __restrict__ hc,
                                                    const int* __restrict__ idx,
                                                    u16* __restrict__ aggc, int M) {
    const int c = blockIdx.x & 7;
    const int base = (blockIdx.x >> 3) * 256;
    __shared__ int soff[256 * SS];
    const int tid = threadIdx.x;
    for (int j = tid; j < 256 * SS; j += 256) {
        int n = base + j / SS;
        if (n >= M) n = M - 1;
        soff[j] = idx[(size_t)n * SS + (j % SS)] * 32;
    }
    __syncthreads();
    const int q = tid & 3;
    const u16* slice = hc + (size_t)c * ((size_t)N_NODES * 32) + q * 8;
    u16* aslice = aggc + (size_t)c * ((size_t)N_NODES * 32) + q * 8;
#pragma unroll 1
    for (int p = 0; p < 4; ++p) {
        const int slot = p * 64 + (tid >> 2);
        const int n = base + slot;
        const int* off = &soff[slot * SS];
        uint4 v[13];
#pragma unroll
        for (int s = 0; s < 13; ++s)
            v[s] = *reinterpret_cast<const uint4*>(slice + off[s]);
        uint4 run = v[0];
#pragma unroll
        for (int s = 1; s < 13; ++s) run = pkmax4(run, v[s]);
#pragma unroll
        for (int s = 13; s < 25; ++s)
            v[s - 13] = *reinterpret_cast<const uint4*>(slice + off[s]);
#pragma unroll
        for (int s = 0; s < 12; ++s) run = pkmax4(run, v[s]);
        if (n < M)
            *reinterpret_cast<uint4*>(aslice + (size_t)n * 32) = run;
    }
}

// ---- bf16 MFMA GEMM, 128x256 tile, 8 waves, A2/B2 dbuf (48KB -> 3 blocks/CU) ----
// out[M,256] = [A1 | A2][M, 32*KT] @ Bf + bias.
// A1 row-major [N][256]; A2 (agg) chunked [8][N][32].
// A staged coalesced (quad-per-row) with XOR slot swizzle (R10-proven addressing).
// Per-iter: vmcnt(0) -> barrier -> stage(kt+1) -> compute(kt); stage latency hides
// under compute + 3-way block interleave (m97/m114 equilibrium).
// OMODE: 0 = bf16 row-major (+relu opt), 1 = bf16 chunked [8][N][32], 2 = f32 row-major.
template <int KT, bool RELU, int OMODE>
__global__ __launch_bounds__(512, 6) void gemm_k(const u16* __restrict__ A1,
                                                 const u16* __restrict__ A2,
                                                 const u16* __restrict__ Bf,
                                                 const float* __restrict__ bias,
                                                 u16* __restrict__ obf,
                                                 float* __restrict__ of32, int M) {
    __shared__ u16 sA[2][4096];  // [row 0..127][slot 0..3][8], 8KB per buf
    __shared__ u16 sB[2][8192];  // 16 frags x 64 lanes x 8, 16KB per buf
    const int tid = threadIdx.x;
    const int lane = tid & 63, w = tid >> 6;
    const int wm = w >> 2, wn = w & 3;  // 2x4 wave grid: 64 rows x 64 cols each
    const int row_base = blockIdx.x * 128;
    const int lr = lane & 15, lk = lane >> 4;

    // staging map: arow = tid>>2 (16 full 64B rows per wave), slot = tid&3
    const int arow = tid >> 2;
    const int swzr = (arow + (arow >> 2)) & 3;
    const int kc = (tid & 3) ^ swzr;  // semantic k-chunk stored at this slot
    int sgrow = row_base + arow;
    if (sgrow >= M) sgrow = M - 1;

    auto stage = [&](int buf, int kt) {
        const u16* srcA = (KT == 16 && kt >= 8)
                              ? A2 + ((size_t)(kt & 7) * N_NODES + sgrow) * 32 + kc * 8
                              : A1 + (size_t)sgrow * DD + (kt & 7) * 32 + kc * 8;
        gld16(&sA[buf][tid * 8], srcA);
#pragma unroll
        for (int j = 0; j < 2; ++j) {
            const int idx = tid + j * 512;
            const int nl = idx >> 6, li = idx & 63;
            gld16(&sB[buf][idx * 8], Bf + ((size_t)(kt * 16 + nl) * 64 + li) * 8);
        }
    };

    f32x4 acc[4][4] = {};
    const int swzl = (lr + (lr >> 2)) & 3;  // swz(row) is wm/m-independent
    auto compute = [&](int buf) {
        bf16x8 a[4], b[4];
#pragma unroll
        for (int m = 0; m < 4; m++) {
            const int row = wm * 64 + m * 16 + lr;
            a[m] = *reinterpret_cast<const bf16x8*>(
                &sA[buf][(row * 4 + (lk ^ swzl)) * 8]);
        }
#pragma unroll
        for (int n = 0; n < 4; n++)
            b[n] = *reinterpret_cast<const bf16x8*>(
                &sB[buf][((wn * 4 + n) * 64 + lane) * 8]);
#pragma unroll
        for (int m = 0; m < 4; m++)
#pragma unroll
            for (int n = 0; n < 4; n++)
                acc[m][n] = __builtin_amdgcn_mfma_f32_16x16x32_bf16(a[m], b[n], acc[m][n], 0, 0, 0);
    };

    stage(0, 0);
#pragma unroll
    for (int kt = 0; kt < KT; ++kt) {
        asm volatile("s_waitcnt vmcnt(0)" ::: "memory");  // stage(kt) landed
        __builtin_amdgcn_s_barrier();                     // buf^1 readers done
        if (kt + 1 < KT) stage((kt + 1) & 1, kt + 1);     // overlaps compute(kt)
        compute(kt & 1);
    }

    // epilogue: wave (wm,wn) owns rows [wm*64,+64) x cols [wn*64,+64)
#pragma unroll
    for (int n = 0; n < 4; n++) {
        const int col = wn * 64 + n * 16 + lr;
        const float bz = bias[col];
#pragma unroll
        for (int m = 0; m < 4; m++) {
            const int r0 = row_base + wm * 64 + m * 16 + lk * 4;
#pragma unroll
            for (int e = 0; e < 4; e++) {
                const int r = r0 + e;
                if (r < M) {
                    float v = acc[m][n][e] + bz;
                    if (RELU) v = fmaxf(v, 0.0f);
                    if (OMODE == 0)
                        obf[(size_t)r * DD + col] = f2bf(v);
                    else if (OMODE == 1)  // chunked: [col>>5][r][col&31]
                        obf[((size_t)(col >> 5) * N_NODES + r) * 32 + (col & 31)] = f2bf(v);
                    else
                        of32[(size_t)r * DD + col] = v;
                }
            }
        }
    }
}

extern "C" void kernel_launch(void* const* d_in, const int* in_sizes, int n_in,
                              void* d_out, int out_size, void* d_ws, size_t ws_size,
                              hipStream_t stream) {
    const float* features = (const float*)d_in[0];
    const int* neigh = (const int*)d_in[1];
    const float* Wp0 = (const float*)d_in[2];
    const float* bp0 = (const float*)d_in[3];
    const float* Wfc0 = (const float*)d_in[4];
    const float* bfc0 = (const float*)d_in[5];
    const float* Wp1 = (const float*)d_in[6];
    const float* bp1 = (const float*)d_in[7];
    const float* Wfc1 = (const float*)d_in[8];
    const float* bfc1 = (const float*)d_in[9];
    float* out = (float*)d_out;

    const size_t ND = (size_t)N_NODES * DD;  // 12.8M
    u16* B0 = (u16*)d_ws;      // X bf16 -> later h1 (chunked)
    u16* B1 = B0 + ND;         // h0 (chunked) -> later O0 (row-major)
    u16* B2 = B1 + ND;         // agg (chunked)
    u16* Wpb0 = B2 + ND;
    u16* Wfb0 = Wpb0 + 65536;
    u16* Wpb1 = Wfb0 + 131072;
    u16* Wfb1 = Wpb1 + 65536;

    cvt_w_k<<<32, 256, 0, stream>>>(Wp0, Wpb0, 8);
    cvt_w_k<<<64, 256, 0, stream>>>(Wfc0, Wfb0, 16);
    cvt_w_k<<<32, 256, 0, stream>>>(Wp1, Wpb1, 8);
    cvt_w_k<<<64, 256, 0, stream>>>(Wfc1, Wfb1, 16);
    cvt_f32_bf16_k<<<12500, 256, 0, stream>>>((const float4*)features, B0);

    const int gg = (N_NODES + 127) / 128;        // 391
    const int gx = ((N_NODES + 255) / 256) * 8;  // 1568

    // ---- layer 0 ----
    gemm_k<8, true, 1><<<gg, 512, 0, stream>>>(B0, nullptr, Wpb0, bp0, B1, nullptr, N_NODES);
    gather_xcd_k<<<gx, 256, 0, stream>>>(B1, neigh, B2, N_NODES);
    gemm_k<16, true, 0><<<gg, 512, 0, stream>>>(B0, B2, Wfb0, bfc0, B1, nullptr, N_NODES);

    // ---- layer 1 ---- (B0 dead -> h1 chunked; B1 holds O0)
    gemm_k<8, true, 1><<<gg, 512, 0, stream>>>(B1, nullptr, Wpb1, bp1, B0, nullptr, N_NODES);
    gather_xcd_k<<<gx, 256, 0, stream>>>(B0, neigh, B2, N_NODES);
    gemm_k<16, false, 2><<<gg, 512, 0, stream>>>(B1, B2, Wfb1, bfc1, nullptr, out, N_NODES);
}

// Round 13
// 213.554 us; speedup vs baseline: 2.3341x; 2.3341x over previous
//
#include <hip/hip_runtime.h>
#include <stdint.h>

#define N_NODES 50000
#define DD 256
#define SS 25

typedef unsigned short u16;
typedef __attribute__((ext_vector_type(8))) __bf16 bf16x8;
typedef __attribute__((ext_vector_type(4))) float f32x4;

__device__ __forceinline__ u16 f2bf(float f) {  // round-to-nearest-even
    union { float f; uint32_t i; } c;
    c.f = f;
    uint32_t r = c.i + 0x7fffu + ((c.i >> 16) & 1u);
    return (u16)(r >> 16);
}

// packed max of 2 non-negative bf16 (bit patterns monotone, sign bit 0 -> signed i16 max is exact)
__device__ __forceinline__ uint4 pkmax4(uint4 a, uint4 b) {
    uint4 d;
    asm("v_pk_max_i16 %0, %1, %2" : "=v"(d.x) : "v"(a.x), "v"(b.x));
    asm("v_pk_max_i16 %0, %1, %2" : "=v"(d.y) : "v"(a.y), "v"(b.y));
    asm("v_pk_max_i16 %0, %1, %2" : "=v"(d.z) : "v"(a.z), "v"(b.z));
    asm("v_pk_max_i16 %0, %1, %2" : "=v"(d.w) : "v"(a.w), "v"(b.w));
    return d;
}

__device__ __forceinline__ void gld16(void* lds, const void* g) {
    __builtin_amdgcn_global_load_lds(
        (const __attribute__((address_space(1))) uint32_t*)g,
        (__attribute__((address_space(3))) uint32_t*)lds, 16, 0, 0);
}

// ---- f32 -> bf16 elementwise (exact: grid*block*4 == n) ----
__global__ __launch_bounds__(256) void cvt_f32_bf16_k(const float4* __restrict__ in,
                                                      u16* __restrict__ out) {
    int i = blockIdx.x * 256 + threadIdx.x;
    float4 v = in[i];
    uint2 o;
    o.x = (uint32_t)f2bf(v.x) | ((uint32_t)f2bf(v.y) << 16);
    o.y = (uint32_t)f2bf(v.z) | ((uint32_t)f2bf(v.w) << 16);
    *reinterpret_cast<uint2*>(out + (size_t)i * 4) = o;
}

// ---- ALL weights f32 [K][256] -> bf16 MFMA B-fragment layout, single dispatch ----
// frag layout: out[((kt*16 + ct)*64 + lane)*8 + e] = W[kt*32 + (lane>>4)*8 + e][ct*16 + (lane&15)]
// t-space: [0,8K) Wp0 | [8K,24K) Wfc0 | [24K,32K) Wp1 | [32K,48K) Wfc1  (K = 1024 t per k-tile)
__global__ __launch_bounds__(256) void cvt_w_all_k(const float* __restrict__ Wp0,
                                                   const float* __restrict__ Wfc0,
                                                   const float* __restrict__ Wp1,
                                                   const float* __restrict__ Wfc1,
                                                   u16* __restrict__ Op0,
                                                   u16* __restrict__ Ofc0,
                                                   u16* __restrict__ Op1,
                                                   u16* __restrict__ Ofc1) {
    int t = blockIdx.x * 256 + threadIdx.x;  // 0 .. 49151
    const float* W;
    u16* out;
    int lt;
    if (t < 8192) {
        W = Wp0; out = Op0; lt = t;
    } else if (t < 24576) {
        W = Wfc0; out = Ofc0; lt = t - 8192;
    } else if (t < 32768) {
        W = Wp1; out = Op1; lt = t - 24576;
    } else {
        W = Wfc1; out = Ofc1; lt = t - 32768;
    }
    int lane = lt & 63;
    int ct = (lt >> 6) & 15;
    int kt = lt >> 10;
    int k0 = kt * 32 + (lane >> 4) * 8;
    int col = ct * 16 + (lane & 15);
    u16 r[8];
#pragma unroll
    for (int e = 0; e < 8; e++) r[e] = f2bf(W[(size_t)(k0 + e) * DD + col]);
    uint4 v;
    v.x = (uint32_t)r[0] | ((uint32_t)r[1] << 16);
    v.y = (uint32_t)r[2] | ((uint32_t)r[3] << 16);
    v.z = (uint32_t)r[4] | ((uint32_t)r[5] << 16);
    v.w = (uint32_t)r[6] | ((uint32_t)r[7] << 16);
    *reinterpret_cast<uint4*>(out + (size_t)lt * 8) = v;
}

// ---- XCD-sliced gather + max-pool (R7-proven, unchanged) ----
__global__ __launch_bounds__(256) void gather_xcd_k(const u16* __restrict__ hc,
                                                    const int* __restrict__ idx,
                                                    u16* __restrict__ aggc, int M) {
    const int c = blockIdx.x & 7;
    const int base = (blockIdx.x >> 3) * 256;
    __shared__ int soff[256 * SS];
    const int tid = threadIdx.x;
    for (int j = tid; j < 256 * SS; j += 256) {
        int n = base + j / SS;
        if (n >= M) n = M - 1;
        soff[j] = idx[(size_t)n * SS + (j % SS)] * 32;
    }
    __syncthreads();
    const int q = tid & 3;
    const u16* slice = hc + (size_t)c * ((size_t)N_NODES * 32) + q * 8;
    u16* aslice = aggc + (size_t)c * ((size_t)N_NODES * 32) + q * 8;
#pragma unroll 1
    for (int p = 0; p < 4; ++p) {
        const int slot = p * 64 + (tid >> 2);
        const int n = base + slot;
        const int* off = &soff[slot * SS];
        uint4 v[13];
#pragma unroll
        for (int s = 0; s < 13; ++s)
            v[s] = *reinterpret_cast<const uint4*>(slice + off[s]);
        uint4 run = v[0];
#pragma unroll
        for (int s = 1; s < 13; ++s) run = pkmax4(run, v[s]);
#pragma unroll
        for (int s = 13; s < 25; ++s)
            v[s - 13] = *reinterpret_cast<const uint4*>(slice + off[s]);
#pragma unroll
        for (int s = 0; s < 12; ++s) run = pkmax4(run, v[s]);
        if (n < M)
            *reinterpret_cast<uint4*>(aslice + (size_t)n * 32) = run;
    }
}

// ---- bf16 MFMA GEMM, 128x256 tile, 8 waves, 4A/3B-stage counted-vmcnt pipeline ----
// (R10-proven, byte-identical.) out[M,256] = [A1 | A2][M, 32*KT] @ Bf + bias.
// A1 row-major [N][256]; A2 (agg) chunked [8][N][32].
// A staged coalesced (quad-per-row) into row-major-64B LDS with XOR slot swizzle
// slot = kc ^ swz(row), swz(r) = (r + (r>>2)) & 3. Issue order B(kt+2), A(kt+3):
// FIFO gives steady vmcnt(4); A ~2.5 iters in flight (HBM), B ~1.5 (L2-hot).
// OMODE: 0 = bf16 row-major (+relu opt), 1 = bf16 chunked [8][N][32], 2 = f32 row-major.
// NOTE (R12 lesson): do NOT raise min-waves/EU — acc[4][4] needs ~64 VGPR; (512,6) spills.
template <int KT, bool RELU, int OMODE>
__global__ __launch_bounds__(512, 4) void gemm_k(const u16* __restrict__ A1,
                                                 const u16* __restrict__ A2,
                                                 const u16* __restrict__ Bf,
                                                 const float* __restrict__ bias,
                                                 u16* __restrict__ obf,
                                                 float* __restrict__ of32, int M) {
    __shared__ u16 sA[4][4096];  // [row 0..127][slot 0..3][8], 8KB per buf
    __shared__ u16 sB[3][8192];  // 16 frags x 64 lanes x 8, 16KB per buf
    const int tid = threadIdx.x;
    const int lane = tid & 63, w = tid >> 6;
    const int wm = w >> 2, wn = w & 3;  // 2x4 wave grid: 64 rows x 64 cols each
    const int row_base = blockIdx.x * 128;
    const int lr = lane & 15, lk = lane >> 4;

    const int arow = tid >> 2;
    const int swzr = (arow + (arow >> 2)) & 3;
    const int kc = (tid & 3) ^ swzr;  // semantic k-chunk stored at this slot
    int sgrow = row_base + arow;
    if (sgrow >= M) sgrow = M - 1;

    auto stageB = [&](int buf, int kt) {
#pragma unroll
        for (int j = 0; j < 2; ++j) {
            const int idx = tid + j * 512;
            const int nl = idx >> 6, li = idx & 63;
            gld16(&sB[buf][idx * 8], Bf + ((size_t)(kt * 16 + nl) * 64 + li) * 8);
        }
    };
    auto stageA = [&](int buf, int kt) {
        const u16* srcA = (KT == 16 && kt >= 8)
                              ? A2 + ((size_t)(kt & 7) * N_NODES + sgrow) * 32 + kc * 8
                              : A1 + (size_t)sgrow * DD + (kt & 7) * 32 + kc * 8;
        gld16(&sA[buf][tid * 8], srcA);
    };

    f32x4 acc[4][4] = {};
    const int swzl = (lr + (lr >> 2)) & 3;  // swz(row) is wm/m-independent
    auto compute = [&](int bufA, int bufB) {
        bf16x8 a[4], b[4];
#pragma unroll
        for (int m = 0; m < 4; m++) {
            const int row = wm * 64 + m * 16 + lr;
            a[m] = *reinterpret_cast<const bf16x8*>(
                &sA[bufA][(row * 4 + (lk ^ swzl)) * 8]);
        }
#pragma unroll
        for (int n = 0; n < 4; n++)
            b[n] = *reinterpret_cast<const bf16x8*>(
                &sB[bufB][((wn * 4 + n) * 64 + lane) * 8]);
#pragma unroll
        for (int m = 0; m < 4; m++)
#pragma unroll
            for (int n = 0; n < 4; n++)
                acc[m][n] = __builtin_amdgcn_mfma_f32_16x16x32_bf16(a[m], b[n], acc[m][n], 0, 0, 0);
    };

    // prologue FIFO: B0,B0,A0,B1,B1,A1,A2  (7 outstanding)
    stageB(0, 0);
    stageA(0, 0);
    stageB(1, 1);
    stageA(1, 1);
    stageA(2, 2);
#pragma unroll
    for (int kt = 0; kt < KT; ++kt) {
        if (kt < KT - 2)
            asm volatile("s_waitcnt vmcnt(4)" ::: "memory");
        else if (kt == KT - 2)
            asm volatile("s_waitcnt vmcnt(3)" ::: "memory");
        else
            asm volatile("s_waitcnt vmcnt(0)" ::: "memory");
        __builtin_amdgcn_s_barrier();
        if (kt + 2 < KT) stageB((kt + 2) % 3, kt + 2);
        if (kt + 3 < KT) stageA((kt + 3) & 3, kt + 3);
        compute(kt & 3, kt % 3);
    }

    // epilogue: wave (wm,wn) owns rows [wm*64,+64) x cols [wn*64,+64)
#pragma unroll
    for (int n = 0; n < 4; n++) {
        const int col = wn * 64 + n * 16 + lr;
        const float bz = bias[col];
#pragma unroll
        for (int m = 0; m < 4; m++) {
            const int r0 = row_base + wm * 64 + m * 16 + lk * 4;
#pragma unroll
            for (int e = 0; e < 4; e++) {
                const int r = r0 + e;
                if (r < M) {
                    float v = acc[m][n][e] + bz;
                    if (RELU) v = fmaxf(v, 0.0f);
                    if (OMODE == 0)
                        obf[(size_t)r * DD + col] = f2bf(v);
                    else if (OMODE == 1)  // chunked: [col>>5][r][col&31]
                        obf[((size_t)(col >> 5) * N_NODES + r) * 32 + (col & 31)] = f2bf(v);
                    else
                        of32[(size_t)r * DD + col] = v;
                }
            }
        }
    }
}

extern "C" void kernel_launch(void* const* d_in, const int* in_sizes, int n_in,
                              void* d_out, int out_size, void* d_ws, size_t ws_size,
                              hipStream_t stream) {
    const float* features = (const float*)d_in[0];
    const int* neigh = (const int*)d_in[1];
    const float* Wp0 = (const float*)d_in[2];
    const float* bp0 = (const float*)d_in[3];
    const float* Wfc0 = (const float*)d_in[4];
    const float* bfc0 = (const float*)d_in[5];
    const float* Wp1 = (const float*)d_in[6];
    const float* bp1 = (const float*)d_in[7];
    const float* Wfc1 = (const float*)d_in[8];
    const float* bfc1 = (const float*)d_in[9];
    float* out = (float*)d_out;

    const size_t ND = (size_t)N_NODES * DD;  // 12.8M
    u16* B0 = (u16*)d_ws;      // X bf16 -> later h1 (chunked)
    u16* B1 = B0 + ND;         // h0 (chunked) -> later O0 (row-major)
    u16* B2 = B1 + ND;         // agg (chunked)
    u16* Wpb0 = B2 + ND;
    u16* Wfb0 = Wpb0 + 65536;
    u16* Wpb1 = Wfb0 + 131072;
    u16* Wfb1 = Wpb1 + 65536;

    cvt_w_all_k<<<192, 256, 0, stream>>>(Wp0, Wfc0, Wp1, Wfc1, Wpb0, Wfb0, Wpb1, Wfb1);
    cvt_f32_bf16_k<<<12500, 256, 0, stream>>>((const float4*)features, B0);

    const int gg = (N_NODES + 127) / 128;        // 391
    const int gx = ((N_NODES + 255) / 256) * 8;  // 1568

    // ---- layer 0 ----
    gemm_k<8, true, 1><<<gg, 512, 0, stream>>>(B0, nullptr, Wpb0, bp0, B1, nullptr, N_NODES);
    gather_xcd_k<<<gx, 256, 0, stream>>>(B1, neigh, B2, N_NODES);
    gemm_k<16, true, 0><<<gg, 512, 0, stream>>>(B0, B2, Wfb0, bfc0, B1, nullptr, N_NODES);

    // ---- layer 1 ---- (B0 dead -> h1 chunked; B1 holds O0)
    gemm_k<8, true, 1><<<gg, 512, 0, stream>>>(B1, nullptr, Wpb1, bp1, B0, nullptr, N_NODES);
    gather_xcd_k<<<gx, 256, 0, stream>>>(B0, neigh, B2, N_NODES);
    gemm_k<16, false, 2><<<gg, 512, 0, stream>>>(B1, B2, Wfb1, bfc1, nullptr, out, N_NODES);
}